// Round 11
// baseline (242.705 us; speedup 1.0000x reference)
//
#include <hip/hip_runtime.h>

namespace {
constexpr int kB = 2;
constexpr int kH = 352;
constexpr int kW = 1216;
constexpr int kHW = kH * kW;        // 428032
constexpr int kN = kB * kHW;        // 856064
constexpr float kDmax = 80.0f;
constexpr float kEps = 1e-6f;
constexpr int kBlock = 256;
}

typedef _Float16 half_t;
typedef __attribute__((ext_vector_type(4))) _Float16 half4;
typedef __attribute__((ext_vector_type(8))) _Float16 half8;

// Module-owned workspace, fully rewritten from inputs on every launch.
__device__ half_t g_Wh[(size_t)48 * kN];  // merged weights, fp16, ch-major (~82 MB)
__device__ float  g_Q[kN];                // fp32 constant term
__device__ float  g_w3[kN];               // per-pixel merged scales (P1 -> P2)
__device__ float  g_w5[kN];
__device__ float  g_w7[kN];
__device__ float  g_ping[kN];             // Dt ping buffer

__device__ __forceinline__ float4 ld4(const float* p) { return *(const float4*)p; }
__device__ __forceinline__ float4 f4add(float4 a, float4 b) {
    return make_float4(a.x + b.x, a.y + b.y, a.z + b.z, a.w + b.w);
}
__device__ __forceinline__ float4 f4mul(float4 a, float4 b) {
    return make_float4(a.x * b.x, a.y * b.y, a.z * b.z, a.w * b.w);
}
__device__ __forceinline__ float4 f4fma(float4 a, float4 b, float4 c) {
    return make_float4(fmaf(a.x, b.x, c.x), fmaf(a.y, b.y, c.y),
                       fmaf(a.z, b.z, c.z), fmaf(a.w, b.w, c.w));
}
__device__ __forceinline__ float4 f4abs(float4 a) {
    return make_float4(fabsf(a.x), fabsf(a.y), fabsf(a.z), fabsf(a.w));
}
__device__ __forceinline__ float4 f4max(float4 a, float4 b) {
    return make_float4(fmaxf(a.x, b.x), fmaxf(a.y, b.y),
                       fmaxf(a.z, b.z), fmaxf(a.w, b.w));
}
__device__ __forceinline__ half4 toh4(float4 v) {
    half4 h;
    h[0] = (half_t)v.x; h[1] = (half_t)v.y; h[2] = (half_t)v.z; h[3] = (half_t)v.w;
    return h;
}

// Async global->LDS copy, 16 B per lane (dest = wave-uniform base + lane*16).
__device__ __forceinline__ void gload_lds16(const float* g, float* l) {
    __builtin_amdgcn_global_load_lds(
        (const __attribute__((address_space(1))) void*)g,
        (__attribute__((address_space(3))) void*)l, 16, 0, 0);
}

// ---- P1: channel-sum pass via width-16 global_load_lds staging. ----
// R10 diagnosis: register-batch streaming pins at 1.47 TB/s (~2 KB in flight
// per CU -- compiler folds buf[8] into load->use chains). Known-fast paths on
// this chip: wide back-to-back VMEM (fill: 7.2 TB/s) and global_load_lds at
// WIDTH 16 (R5/R6 used width 4 -> 1.8 TB/s). m97 pattern: stage 8 channel
// slabs (32 KB) per group async into LDS, barrier, consume via ds_read_b128.
// 5 blocks/CU overlap staging with consuming (m114 wave-level overlap).
__global__ __launch_bounds__(kBlock) void prep1_kernel(
    const float* __restrict__ D0, const float* __restrict__ DL,
    const float* __restrict__ ML, const float* __restrict__ A3,
    const float* __restrict__ A5, const float* __restrict__ A7,
    const float* __restrict__ SG, const float* __restrict__ AL)
{
    __shared__ float buf[8 * 1024];           // 32 KB -> up to 5 blocks/CU

    int tid = threadIdx.x;
    int pblk = blockIdx.x * (kBlock * 4);     // block's first pixel; kHW%1024==0
    int b = pblk / kHW;
    int rem0 = pblk - b * kHW;
    int p = pblk + tid * 4;                   // this thread's 4 pixels

    const float* a3b = A3 + (size_t)b * 9 * kHW + rem0;
    const float* a5b = A5 + (size_t)b * 25 * kHW + rem0;
    const float* a7b = A7 + (size_t)b * 49 * kHW + rem0;
    const float* sgb = SG + (size_t)b * 3 * kHW + rem0;

    int lds_wbase = (tid >> 6) * 256;         // wave-uniform LDS float offset
    int goff = tid * 4;                       // per-lane global float offset

    float4 zero = make_float4(0.f, 0.f, 0.f, 0.f);
    float4 s7v = zero, s5v = zero, s3v = zero;
    float4 c7v = zero, c5v = zero, c3v = zero;

    // Slab order: a7[0..48], a5[0..24], a3[0..8]  (83 slabs = 10x8 + 3)
#pragma unroll
    for (int ggrp = 0; ggrp < 11; ++ggrp) {
        const int ng = (ggrp < 10) ? 8 : 3;
#pragma unroll
        for (int j = 0; j < 8; ++j) {
            if (j >= ng) break;
            int s = ggrp * 8 + j;
            const float* slab;
            if (s < 49)      slab = a7b + (size_t)s * kHW;
            else if (s < 74) slab = a5b + (size_t)(s - 49) * kHW;
            else             slab = a3b + (size_t)(s - 74) * kHW;
            gload_lds16(slab + goff, &buf[j * 1024 + lds_wbase]);
        }
        __syncthreads();   // drains vmcnt -> staged data valid
#pragma unroll
        for (int j = 0; j < 8; ++j) {
            if (j >= ng) break;
            int s = ggrp * 8 + j;
            float4 v = ld4(&buf[j * 1024 + tid * 4]);
            if (s < 49) {
                if (s == 24) c7v = v;
                s7v = f4add(s7v, f4abs(v));
            } else if (s < 74) {
                if (s == 61) c5v = v;
                s5v = f4add(s5v, f4abs(v));
            } else {
                if (s == 78) c3v = v;
                s3v = f4add(s3v, f4abs(v));
            }
        }
        __syncthreads();   // WAR: safe to overwrite buf next group
    }

    // Small per-pixel inputs (direct float4 loads).
    float4 g0 = ld4(sgb + goff);
    float4 g1 = ld4(sgb + kHW + goff);
    float4 g2 = ld4(sgb + 2 * kHW + goff);
    float4 mx = f4max(g0, f4max(g1, g2));
    float4 e0 = make_float4(expf(g0.x - mx.x), expf(g0.y - mx.y), expf(g0.z - mx.z), expf(g0.w - mx.w));
    float4 e1 = make_float4(expf(g1.x - mx.x), expf(g1.y - mx.y), expf(g1.z - mx.z), expf(g1.w - mx.w));
    float4 e2 = make_float4(expf(g2.x - mx.x), expf(g2.y - mx.y), expf(g2.z - mx.z), expf(g2.w - mx.w));
    float4 einv = make_float4(1.f / (e0.x + e1.x + e2.x), 1.f / (e0.y + e1.y + e2.y),
                              1.f / (e0.z + e1.z + e2.z), 1.f / (e0.w + e1.w + e2.w));

    float4 alv = ld4(AL + p);
    float4 ml  = ld4(ML + p);
    float4 al = make_float4(fminf(fmaxf(alv.x, 0.f), 1.f), fminf(fmaxf(alv.y, 0.f), 1.f),
                            fminf(fmaxf(alv.z, 0.f), 1.f), fminf(fmaxf(alv.w, 0.f), 1.f));
    float4 mk = make_float4(ml.x > 0.5f ? 1.f : 0.f, ml.y > 0.5f ? 1.f : 0.f,
                            ml.z > 0.5f ? 1.f : 0.f, ml.w > 0.5f ? 1.f : 0.f);
    float4 g = f4mul(al, mk);
    float4 omg = make_float4(1.f - g.x, 1.f - g.y, 1.f - g.z, 1.f - g.w);

    float4 w3 = make_float4(omg.x * e0.x * einv.x / (s3v.x + kEps), omg.y * e0.y * einv.y / (s3v.y + kEps),
                            omg.z * e0.z * einv.z / (s3v.z + kEps), omg.w * e0.w * einv.w / (s3v.w + kEps));
    float4 w5 = make_float4(omg.x * e1.x * einv.x / (s5v.x + kEps), omg.y * e1.y * einv.y / (s5v.y + kEps),
                            omg.z * e1.z * einv.z / (s5v.z + kEps), omg.w * e1.w * einv.w / (s5v.w + kEps));
    float4 w7 = make_float4(omg.x * e2.x * einv.x / (s7v.x + kEps), omg.y * e2.y * einv.y / (s7v.y + kEps),
                            omg.z * e2.z * einv.z / (s7v.z + kEps), omg.w * e2.w * einv.w / (s7v.w + kEps));

    float4 d0 = ld4(D0 + p);
    float4 dl = ld4(DL + p);
    float4 cw = f4fma(w3, c3v, f4fma(w5, c5v, f4mul(w7, c7v)));
    *(float4*)(&g_Q[p])  = f4fma(cw, d0, f4mul(g, dl));
    *(float4*)(&g_w3[p]) = w3;
    *(float4*)(&g_w5[p]) = w5;
    *(float4*)(&g_w7[p]) = w7;
}

// ---- P2: merge pass, REVERSED block order (L3 hits on re-read). ----
__global__ __launch_bounds__(kBlock) void prep2_kernel(
    const float* __restrict__ A3, const float* __restrict__ A5,
    const float* __restrict__ A7)
{
    int blk = gridDim.x - 1 - blockIdx.x;        // reversed
    int t = blk * kBlock + threadIdx.x;
    int p = t * 4;
    int b = p / kHW;
    int rem = p - b * kHW;

    const float* a3p = A3 + (size_t)b * 9 * kHW + rem;
    const float* a5p = A5 + (size_t)b * 25 * kHW + rem;
    const float* a7p = A7 + (size_t)b * 49 * kHW + rem;

    float4 w3 = ld4(&g_w3[p]);
    float4 w5 = ld4(&g_w5[p]);
    float4 w7 = ld4(&g_w7[p]);

    int oi = 0;
#pragma unroll
    for (int i = 0; i < 49; ++i) {
        int dy = i / 7 - 3, dx = i % 7 - 3;
        if (dy == 0 && dx == 0) continue;        // center Dt coef cancels
        float4 wv = f4mul(w7, ld4(a7p + (size_t)i * kHW));
        if (dy >= -2 && dy <= 2 && dx >= -2 && dx <= 2)
            wv = f4fma(w5, ld4(a5p + (size_t)((dy + 2) * 5 + (dx + 2)) * kHW), wv);
        if (dy >= -1 && dy <= 1 && dx >= -1 && dx <= 1)
            wv = f4fma(w3, ld4(a3p + (size_t)((dy + 1) * 3 + (dx + 1)) * kHW), wv);
        *(half4*)(&g_Wh[(size_t)oi * kN + p]) = toh4(wv);
        ++oi;
    }
}

// One propagation step, 8 pixels/thread (unchanged from R10: ~11 us).
__global__ __launch_bounds__(kBlock) void step_kernel(
    const float* __restrict__ Din_ext, float* __restrict__ Dout_ext,
    int src_g, int dst_g)
{
    const float* Din = src_g ? g_ping : Din_ext;
    float* Dout = dst_g ? g_ping : Dout_ext;

    int t = blockIdx.x * kBlock + threadIdx.x;   // 0 .. kN/8-1
    int p = t * 8;
    int b = p / kHW;                             // kHW % 8 == 0
    int rem = p - b * kHW;
    int y = rem / kW;                            // kW % 8 == 0: stays in one row
    int x0 = rem - y * kW;
    const float* dinb = Din + (size_t)b * kHW;

    float acc[8];
    {
        float4 q0 = ld4(&g_Q[p]);
        float4 q1 = ld4(&g_Q[p + 4]);
        acc[0] = q0.x; acc[1] = q0.y; acc[2] = q0.z; acc[3] = q0.w;
        acc[4] = q1.x; acc[5] = q1.y; acc[6] = q1.z; acc[7] = q1.w;
    }

    int oi = 0;
#pragma unroll
    for (int dy = -3; dy <= 3; ++dy) {
        int ny = y + dy;
        bool rv = (ny >= 0) && (ny < kH);
        if (!rv) { oi += (dy == 0) ? 6 : 7; continue; }   // zero contribution
        const float* dr = dinb + ny * kW;

        float rowv[16];   // covers x0-4 .. x0+11
#pragma unroll
        for (int s = 0; s < 4; ++s) {
            int xb = x0 + (s - 1) * 4;
            float4 v = (xb >= 0 && xb + 3 < kW) ? ld4(dr + xb)
                                                : make_float4(0.f, 0.f, 0.f, 0.f);
            rowv[s * 4 + 0] = v.x; rowv[s * 4 + 1] = v.y;
            rowv[s * 4 + 2] = v.z; rowv[s * 4 + 3] = v.w;
        }
#pragma unroll
        for (int dx = -3; dx <= 3; ++dx) {
            if (dy == 0 && dx == 0) continue;
            half8 w = *(const half8*)(&g_Wh[(size_t)oi * kN + p]);
#pragma unroll
            for (int j = 0; j < 8; ++j)
                acc[j] = fmaf((float)w[j], rowv[4 + j + dx], acc[j]);
            ++oi;
        }
    }

#pragma unroll
    for (int j = 0; j < 8; ++j)
        acc[j] = fminf(fmaxf(acc[j], 0.f), kDmax);
    *(float4*)(&Dout[p])     = make_float4(acc[0], acc[1], acc[2], acc[3]);
    *(float4*)(&Dout[p + 4]) = make_float4(acc[4], acc[5], acc[6], acc[7]);
}

extern "C" void kernel_launch(void* const* d_in, const int* in_sizes, int n_in,
                              void* d_out, int out_size, void* d_ws, size_t ws_size,
                              hipStream_t stream) {
    const float* D0 = (const float*)d_in[0];
    const float* DL = (const float*)d_in[1];
    const float* ML = (const float*)d_in[2];
    const float* A3 = (const float*)d_in[3];
    const float* A5 = (const float*)d_in[4];
    const float* A7 = (const float*)d_in[5];
    const float* SG = (const float*)d_in[6];
    const float* AL = (const float*)d_in[7];
    float* out = (float*)d_out;

    dim3 block(kBlock);
    dim3 gridQ(kN / 4 / kBlock);   // 836, exact
    dim3 gridO(kN / 8 / kBlock);   // 418, exact

    prep1_kernel<<<gridQ, block, 0, stream>>>(D0, DL, ML, A3, A5, A7, SG, AL);
    prep2_kernel<<<gridQ, block, 0, stream>>>(A3, A5, A7);

    // Chain: D0 -> ping -> out -> ping -> out -> ping -> out
    step_kernel<<<gridO, block, 0, stream>>>(D0, nullptr, 0, 1);
    step_kernel<<<gridO, block, 0, stream>>>(nullptr, out, 1, 0);
    step_kernel<<<gridO, block, 0, stream>>>(out, nullptr, 0, 1);
    step_kernel<<<gridO, block, 0, stream>>>(nullptr, out, 1, 0);
    step_kernel<<<gridO, block, 0, stream>>>(out, nullptr, 0, 1);
    step_kernel<<<gridO, block, 0, stream>>>(nullptr, out, 1, 0);
}

// Round 12
// 240.355 us; speedup vs baseline: 1.0098x; 1.0098x over previous
//
#include <hip/hip_runtime.h>

namespace {
constexpr int kB = 2;
constexpr int kH = 352;
constexpr int kW = 1216;
constexpr int kHW = kH * kW;        // 428032
constexpr int kN = kB * kHW;        // 856064
constexpr float kDmax = 80.0f;
constexpr float kEps = 1e-6f;
constexpr int kBlock = 256;
}

typedef _Float16 half_t;
typedef __attribute__((ext_vector_type(4))) _Float16 half4;
typedef __attribute__((ext_vector_type(8))) _Float16 half8;

// Module-owned workspace, fully rewritten from inputs on every launch.
__device__ half_t g_Wh[(size_t)48 * kN];  // merged weights, fp16, ch-major (~82 MB)
__device__ float  g_Q[kN];                // fp32 constant term
__device__ float  g_w3[kN];               // per-pixel merged scales (P1 -> P2)
__device__ float  g_w5[kN];
__device__ float  g_w7[kN];
__device__ float  g_ping[kN];             // Dt ping buffer

__device__ __forceinline__ float4 ld4(const float* p) { return *(const float4*)p; }
__device__ __forceinline__ float4 f4add(float4 a, float4 b) {
    return make_float4(a.x + b.x, a.y + b.y, a.z + b.z, a.w + b.w);
}
__device__ __forceinline__ float4 f4mul(float4 a, float4 b) {
    return make_float4(a.x * b.x, a.y * b.y, a.z * b.z, a.w * b.w);
}
__device__ __forceinline__ float4 f4fma(float4 a, float4 b, float4 c) {
    return make_float4(fmaf(a.x, b.x, c.x), fmaf(a.y, b.y, c.y),
                       fmaf(a.z, b.z, c.z), fmaf(a.w, b.w, c.w));
}
__device__ __forceinline__ float4 f4abs(float4 a) {
    return make_float4(fabsf(a.x), fabsf(a.y), fabsf(a.z), fabsf(a.w));
}
__device__ __forceinline__ float4 f4max(float4 a, float4 b) {
    return make_float4(fmaxf(a.x, b.x), fmaxf(a.y, b.y),
                       fmaxf(a.z, b.z), fmaxf(a.w, b.w));
}
__device__ __forceinline__ half4 toh4(float4 v) {
    half4 h;
    h[0] = (half_t)v.x; h[1] = (half_t)v.y; h[2] = (half_t)v.z; h[3] = (half_t)v.w;
    return h;
}

// Async global->LDS copy, 16 B per lane (dest = wave-uniform base + lane*16).
__device__ __forceinline__ void gload_lds16(const float* g, float* l) {
    __builtin_amdgcn_global_load_lds(
        (const __attribute__((address_space(1))) void*)g,
        (__attribute__((address_space(3))) void*)l, 16, 0, 0);
}

// Slab s (0..82): a7[0..48] | a5[0..24] | a3[0..8]
__device__ __forceinline__ const float* slab_ptr(int s, const float* a7b,
                                                 const float* a5b, const float* a3b) {
    return (s < 49) ? a7b + (size_t)s * kHW
         : (s < 74) ? a5b + (size_t)(s - 49) * kHW
                    : a3b + (size_t)(s - 74) * kHW;
}

template<int G>
__device__ __forceinline__ void issue_group(const float* a7b, const float* a5b,
                                            const float* a3b, int goff,
                                            float* buf, int lds_wbase) {
#pragma unroll
    for (int j = 0; j < 8; ++j) {
        const int s = G * 8 + j;
        if (s < 83)
            gload_lds16(slab_ptr(s, a7b, a5b, a3b) + goff,
                        &buf[(G & 1) * 8192 + j * 1024 + lds_wbase]);
    }
}

template<int G>
__device__ __forceinline__ void consume_group(
    const float* buf, int tid4,
    float4& s7v, float4& s5v, float4& s3v,
    float4& c7v, float4& c5v, float4& c3v) {
#pragma unroll
    for (int j = 0; j < 8; ++j) {
        const int s = G * 8 + j;
        if (s < 83) {
            float4 v = ld4(&buf[(G & 1) * 8192 + j * 1024 + tid4]);
            if (s < 49)      { if (s == 24) c7v = v; s7v = f4add(s7v, f4abs(v)); }
            else if (s < 74) { if (s == 61) c5v = v; s5v = f4add(s5v, f4abs(v)); }
            else             { if (s == 78) c3v = v; s3v = f4add(s3v, f4abs(v)); }
        }
    }
}

// ---- P1: channel-sum pass, counted-vmcnt DMA pipeline (T3/T4), barrier-free.
// R11 diagnosis: replays fetch only 13.8 MB (L3-warm) yet still run 115 us at
// 119 GB/s -> pure latency-bound; the per-group __syncthreads forced a
// vmcnt(0) drain every 8 loads. Staging here is WAVE-LOCAL (each wave's DMA
// fills the segment only its own lanes read), so no barriers are needed:
// 2-deep double-buffered groups, s_waitcnt vmcnt(8) in steady state (one
// group always in flight across the consume), lgkmcnt(0) before re-issuing
// into a consumed buffer (DMA and ds_read are separate HW queues). Waves
// drift freely; 2 blocks/CU; 16 KB DMA in flight per wave.
__global__ __launch_bounds__(kBlock) void prep1_kernel(
    const float* __restrict__ D0, const float* __restrict__ DL,
    const float* __restrict__ ML, const float* __restrict__ A3,
    const float* __restrict__ A5, const float* __restrict__ A7,
    const float* __restrict__ SG, const float* __restrict__ AL)
{
    __shared__ float buf[2 * 8 * 1024];       // 64 KB -> 2 blocks/CU

    int tid = threadIdx.x;
    int pblk = blockIdx.x * (kBlock * 4);     // kHW % 1024 == 0: batch-uniform
    int b = pblk / kHW;
    int rem0 = pblk - b * kHW;
    int p = pblk + tid * 4;

    const float* a3b = A3 + (size_t)b * 9 * kHW + rem0;
    const float* a5b = A5 + (size_t)b * 25 * kHW + rem0;
    const float* a7b = A7 + (size_t)b * 49 * kHW + rem0;
    const float* sgb = SG + (size_t)b * 3 * kHW + rem0;

    int lds_wbase = (tid >> 6) * 256;         // wave-uniform LDS float offset
    int goff = tid * 4;                       // per-lane global float offset
    int tid4 = tid * 4;

    float4 zero = make_float4(0.f, 0.f, 0.f, 0.f);
    float4 s7v = zero, s5v = zero, s3v = zero;
    float4 c7v = zero, c5v = zero, c3v = zero;

    // Prologue: 2 groups in flight.
    issue_group<0>(a7b, a5b, a3b, goff, buf, lds_wbase);
    issue_group<1>(a7b, a5b, a3b, goff, buf, lds_wbase);

    // Steady state: wait for oldest group only (vmcnt(8) = newest group stays
    // in flight), consume, drain own ds_reads, re-issue into freed buffer.
#define PIPE_STEP(G, WAITSTR)                                              \
    asm volatile("s_waitcnt " WAITSTR ::: "memory");                       \
    consume_group<G>(buf, tid4, s7v, s5v, s3v, c7v, c5v, c3v);             \
    asm volatile("s_waitcnt lgkmcnt(0)" ::: "memory");

    PIPE_STEP(0, "vmcnt(8)") issue_group<2>(a7b, a5b, a3b, goff, buf, lds_wbase);
    PIPE_STEP(1, "vmcnt(8)") issue_group<3>(a7b, a5b, a3b, goff, buf, lds_wbase);
    PIPE_STEP(2, "vmcnt(8)") issue_group<4>(a7b, a5b, a3b, goff, buf, lds_wbase);
    PIPE_STEP(3, "vmcnt(8)") issue_group<5>(a7b, a5b, a3b, goff, buf, lds_wbase);
    PIPE_STEP(4, "vmcnt(8)") issue_group<6>(a7b, a5b, a3b, goff, buf, lds_wbase);
    PIPE_STEP(5, "vmcnt(8)") issue_group<7>(a7b, a5b, a3b, goff, buf, lds_wbase);
    PIPE_STEP(6, "vmcnt(8)") issue_group<8>(a7b, a5b, a3b, goff, buf, lds_wbase);
    PIPE_STEP(7, "vmcnt(8)") issue_group<9>(a7b, a5b, a3b, goff, buf, lds_wbase);
    PIPE_STEP(8, "vmcnt(8)") issue_group<10>(a7b, a5b, a3b, goff, buf, lds_wbase);
    PIPE_STEP(9, "vmcnt(3)")   // group 10 (3 slabs) still in flight
    PIPE_STEP(10, "vmcnt(0)")
#undef PIPE_STEP

    // Small per-pixel inputs (direct float4 loads; after the pipeline these
    // can only lengthen waits if hoisted -- vmcnt waits oldest-first).
    float4 g0 = ld4(sgb + goff);
    float4 g1 = ld4(sgb + kHW + goff);
    float4 g2 = ld4(sgb + 2 * kHW + goff);
    float4 mx = f4max(g0, f4max(g1, g2));
    float4 e0 = make_float4(expf(g0.x - mx.x), expf(g0.y - mx.y), expf(g0.z - mx.z), expf(g0.w - mx.w));
    float4 e1 = make_float4(expf(g1.x - mx.x), expf(g1.y - mx.y), expf(g1.z - mx.z), expf(g1.w - mx.w));
    float4 e2 = make_float4(expf(g2.x - mx.x), expf(g2.y - mx.y), expf(g2.z - mx.z), expf(g2.w - mx.w));
    float4 einv = make_float4(1.f / (e0.x + e1.x + e2.x), 1.f / (e0.y + e1.y + e2.y),
                              1.f / (e0.z + e1.z + e2.z), 1.f / (e0.w + e1.w + e2.w));

    float4 alv = ld4(AL + p);
    float4 ml  = ld4(ML + p);
    float4 al = make_float4(fminf(fmaxf(alv.x, 0.f), 1.f), fminf(fmaxf(alv.y, 0.f), 1.f),
                            fminf(fmaxf(alv.z, 0.f), 1.f), fminf(fmaxf(alv.w, 0.f), 1.f));
    float4 mk = make_float4(ml.x > 0.5f ? 1.f : 0.f, ml.y > 0.5f ? 1.f : 0.f,
                            ml.z > 0.5f ? 1.f : 0.f, ml.w > 0.5f ? 1.f : 0.f);
    float4 g = f4mul(al, mk);
    float4 omg = make_float4(1.f - g.x, 1.f - g.y, 1.f - g.z, 1.f - g.w);

    float4 w3 = make_float4(omg.x * e0.x * einv.x / (s3v.x + kEps), omg.y * e0.y * einv.y / (s3v.y + kEps),
                            omg.z * e0.z * einv.z / (s3v.z + kEps), omg.w * e0.w * einv.w / (s3v.w + kEps));
    float4 w5 = make_float4(omg.x * e1.x * einv.x / (s5v.x + kEps), omg.y * e1.y * einv.y / (s5v.y + kEps),
                            omg.z * e1.z * einv.z / (s5v.z + kEps), omg.w * e1.w * einv.w / (s5v.w + kEps));
    float4 w7 = make_float4(omg.x * e2.x * einv.x / (s7v.x + kEps), omg.y * e2.y * einv.y / (s7v.y + kEps),
                            omg.z * e2.z * einv.z / (s7v.z + kEps), omg.w * e2.w * einv.w / (s7v.w + kEps));

    float4 d0 = ld4(D0 + p);
    float4 dl = ld4(DL + p);
    float4 cw = f4fma(w3, c3v, f4fma(w5, c5v, f4mul(w7, c7v)));
    *(float4*)(&g_Q[p])  = f4fma(cw, d0, f4mul(g, dl));
    *(float4*)(&g_w3[p]) = w3;
    *(float4*)(&g_w5[p]) = w5;
    *(float4*)(&g_w7[p]) = w7;
}

// ---- P2: merge pass, REVERSED block order (L3 hits on re-read). ----
__global__ __launch_bounds__(kBlock) void prep2_kernel(
    const float* __restrict__ A3, const float* __restrict__ A5,
    const float* __restrict__ A7)
{
    int blk = gridDim.x - 1 - blockIdx.x;        // reversed
    int t = blk * kBlock + threadIdx.x;
    int p = t * 4;
    int b = p / kHW;
    int rem = p - b * kHW;

    const float* a3p = A3 + (size_t)b * 9 * kHW + rem;
    const float* a5p = A5 + (size_t)b * 25 * kHW + rem;
    const float* a7p = A7 + (size_t)b * 49 * kHW + rem;

    float4 w3 = ld4(&g_w3[p]);
    float4 w5 = ld4(&g_w5[p]);
    float4 w7 = ld4(&g_w7[p]);

    int oi = 0;
#pragma unroll
    for (int i = 0; i < 49; ++i) {
        int dy = i / 7 - 3, dx = i % 7 - 3;
        if (dy == 0 && dx == 0) continue;        // center Dt coef cancels
        float4 wv = f4mul(w7, ld4(a7p + (size_t)i * kHW));
        if (dy >= -2 && dy <= 2 && dx >= -2 && dx <= 2)
            wv = f4fma(w5, ld4(a5p + (size_t)((dy + 2) * 5 + (dx + 2)) * kHW), wv);
        if (dy >= -1 && dy <= 1 && dx >= -1 && dx <= 1)
            wv = f4fma(w3, ld4(a3p + (size_t)((dy + 1) * 3 + (dx + 1)) * kHW), wv);
        *(half4*)(&g_Wh[(size_t)oi * kN + p]) = toh4(wv);
        ++oi;
    }
}

// One propagation step, 8 pixels/thread (unchanged: ~11 us).
__global__ __launch_bounds__(kBlock) void step_kernel(
    const float* __restrict__ Din_ext, float* __restrict__ Dout_ext,
    int src_g, int dst_g)
{
    const float* Din = src_g ? g_ping : Din_ext;
    float* Dout = dst_g ? g_ping : Dout_ext;

    int t = blockIdx.x * kBlock + threadIdx.x;   // 0 .. kN/8-1
    int p = t * 8;
    int b = p / kHW;                             // kHW % 8 == 0
    int rem = p - b * kHW;
    int y = rem / kW;                            // kW % 8 == 0: stays in one row
    int x0 = rem - y * kW;
    const float* dinb = Din + (size_t)b * kHW;

    float acc[8];
    {
        float4 q0 = ld4(&g_Q[p]);
        float4 q1 = ld4(&g_Q[p + 4]);
        acc[0] = q0.x; acc[1] = q0.y; acc[2] = q0.z; acc[3] = q0.w;
        acc[4] = q1.x; acc[5] = q1.y; acc[6] = q1.z; acc[7] = q1.w;
    }

    int oi = 0;
#pragma unroll
    for (int dy = -3; dy <= 3; ++dy) {
        int ny = y + dy;
        bool rv = (ny >= 0) && (ny < kH);
        if (!rv) { oi += (dy == 0) ? 6 : 7; continue; }   // zero contribution
        const float* dr = dinb + ny * kW;

        float rowv[16];   // covers x0-4 .. x0+11
#pragma unroll
        for (int s = 0; s < 4; ++s) {
            int xb = x0 + (s - 1) * 4;
            float4 v = (xb >= 0 && xb + 3 < kW) ? ld4(dr + xb)
                                                : make_float4(0.f, 0.f, 0.f, 0.f);
            rowv[s * 4 + 0] = v.x; rowv[s * 4 + 1] = v.y;
            rowv[s * 4 + 2] = v.z; rowv[s * 4 + 3] = v.w;
        }
#pragma unroll
        for (int dx = -3; dx <= 3; ++dx) {
            if (dy == 0 && dx == 0) continue;
            half8 w = *(const half8*)(&g_Wh[(size_t)oi * kN + p]);
#pragma unroll
            for (int j = 0; j < 8; ++j)
                acc[j] = fmaf((float)w[j], rowv[4 + j + dx], acc[j]);
            ++oi;
        }
    }

#pragma unroll
    for (int j = 0; j < 8; ++j)
        acc[j] = fminf(fmaxf(acc[j], 0.f), kDmax);
    *(float4*)(&Dout[p])     = make_float4(acc[0], acc[1], acc[2], acc[3]);
    *(float4*)(&Dout[p + 4]) = make_float4(acc[4], acc[5], acc[6], acc[7]);
}

extern "C" void kernel_launch(void* const* d_in, const int* in_sizes, int n_in,
                              void* d_out, int out_size, void* d_ws, size_t ws_size,
                              hipStream_t stream) {
    const float* D0 = (const float*)d_in[0];
    const float* DL = (const float*)d_in[1];
    const float* ML = (const float*)d_in[2];
    const float* A3 = (const float*)d_in[3];
    const float* A5 = (const float*)d_in[4];
    const float* A7 = (const float*)d_in[5];
    const float* SG = (const float*)d_in[6];
    const float* AL = (const float*)d_in[7];
    float* out = (float*)d_out;

    dim3 block(kBlock);
    dim3 gridQ(kN / 4 / kBlock);   // 836, exact
    dim3 gridO(kN / 8 / kBlock);   // 418, exact

    prep1_kernel<<<gridQ, block, 0, stream>>>(D0, DL, ML, A3, A5, A7, SG, AL);
    prep2_kernel<<<gridQ, block, 0, stream>>>(A3, A5, A7);

    // Chain: D0 -> ping -> out -> ping -> out -> ping -> out
    step_kernel<<<gridO, block, 0, stream>>>(D0, nullptr, 0, 1);
    step_kernel<<<gridO, block, 0, stream>>>(nullptr, out, 1, 0);
    step_kernel<<<gridO, block, 0, stream>>>(out, nullptr, 0, 1);
    step_kernel<<<gridO, block, 0, stream>>>(nullptr, out, 1, 0);
    step_kernel<<<gridO, block, 0, stream>>>(out, nullptr, 0, 1);
    step_kernel<<<gridO, block, 0, stream>>>(nullptr, out, 1, 0);
}

// Round 13
// 196.397 us; speedup vs baseline: 1.2358x; 1.2238x over previous
//
#include <hip/hip_runtime.h>

namespace {
constexpr int kB = 2;
constexpr int kH = 352;
constexpr int kW = 1216;
constexpr int kHW = kH * kW;        // 428032
constexpr int kN = kB * kHW;        // 856064
constexpr float kDmax = 80.0f;
constexpr float kEps = 1e-6f;
constexpr int kBlock = 256;
}

typedef _Float16 half_t;
typedef __attribute__((ext_vector_type(4))) _Float16 half4;
typedef __attribute__((ext_vector_type(8))) _Float16 half8;

// Module-owned workspace, fully rewritten from inputs on every launch.
__device__ half_t g_Wh[(size_t)48 * kN];  // merged weights, fp16, ch-major (~82 MB)
__device__ float  g_Q[kN];                // fp32 constant term
__device__ float  g_ping[kN];             // Dt ping buffer

__device__ __forceinline__ float4 ld4(const float* p) { return *(const float4*)p; }
__device__ __forceinline__ float4 f4add(float4 a, float4 b) {
    return make_float4(a.x + b.x, a.y + b.y, a.z + b.z, a.w + b.w);
}
__device__ __forceinline__ float4 f4mul(float4 a, float4 b) {
    return make_float4(a.x * b.x, a.y * b.y, a.z * b.z, a.w * b.w);
}
__device__ __forceinline__ float4 f4fma(float4 a, float4 b, float4 c) {
    return make_float4(fmaf(a.x, b.x, c.x), fmaf(a.y, b.y, c.y),
                       fmaf(a.z, b.z, c.z), fmaf(a.w, b.w, c.w));
}
__device__ __forceinline__ float4 f4abs(float4 a) {
    return make_float4(fabsf(a.x), fabsf(a.y), fabsf(a.z), fabsf(a.w));
}
__device__ __forceinline__ float4 f4max(float4 a, float4 b) {
    return make_float4(fmaxf(a.x, b.x), fmaxf(a.y, b.y),
                       fmaxf(a.z, b.z), fmaxf(a.w, b.w));
}
__device__ __forceinline__ half4 toh4(float4 v) {
    half4 h;
    h[0] = (half_t)v.x; h[1] = (half_t)v.y; h[2] = (half_t)v.z; h[3] = (half_t)v.w;
    return h;
}
__device__ __forceinline__ float4 tof4(half4 h) {
    return make_float4((float)h[0], (float)h[1], (float)h[2], (float)h[3]);
}

// Single-pass merged-weight precompute (R9 kernel, verbatim — measured 128 us,
// ideal traffic: read inputs once, write Wh+Q once).
// R12 meta-lesson: 11 structural variants all land at 108-143 us for the cold
// input read => this chip's cold HBM READ rate (~1.4-2 TB/s HBM-side, ~2.8
// TB/s demand w/ L3) is the wall; occupancy/width/pipelining don't move it.
// So pay the wall ONCE: stash a7+a5 fp16 in LDS (148 KB, per-thread-private
// slots, no barriers), a3 in 36 VGPRs; merge reads LDS, never re-reads HBM.
__global__ __launch_bounds__(kBlock, 2) void prep_kernel(
    const float* __restrict__ D0, const float* __restrict__ DL,
    const float* __restrict__ ML, const float* __restrict__ A3,
    const float* __restrict__ A5, const float* __restrict__ A7,
    const float* __restrict__ SG, const float* __restrict__ AL)
{
    __shared__ half_t sh7[49 * kBlock * 4];   // 100352 B
    __shared__ half_t sh5[25 * kBlock * 4];   //  51200 B  (total 148 KiB)

    int tid = threadIdx.x;
    int t = blockIdx.x * kBlock + tid;        // 0 .. kN/4-1
    int p = t * 4;
    int b = p / kHW;                          // kHW % 1024 == 0: block batch-uniform
    int rem = p - b * kHW;
    int sb = tid * 4;                         // this thread's LDS pixel base

    const float* a3p = A3 + (size_t)b * 9 * kHW + rem;
    const float* a5p = A5 + (size_t)b * 25 * kHW + rem;
    const float* a7p = A7 + (size_t)b * 49 * kHW + rem;
    const float* sgp = SG + (size_t)b * 3 * kHW + rem;

    float4 zero = make_float4(0.f, 0.f, 0.f, 0.f);

    // ---- Stream a7: 6x8 batches + 1; abs-sum, stash fp16 ----
    float4 s7v = zero, c7v = zero;
#pragma unroll
    for (int ch = 0; ch < 6; ++ch) {
        float4 buf[8];
#pragma unroll
        for (int j = 0; j < 8; ++j) buf[j] = ld4(a7p + (size_t)(ch * 8 + j) * kHW);
#pragma unroll
        for (int j = 0; j < 8; ++j) {
            int c = ch * 8 + j;
            if (c == 24) c7v = buf[j];
            s7v = f4add(s7v, f4abs(buf[j]));
            *(half4*)(&sh7[c * (kBlock * 4) + sb]) = toh4(buf[j]);
        }
    }
    {
        float4 l = ld4(a7p + (size_t)48 * kHW);
        s7v = f4add(s7v, f4abs(l));
        *(half4*)(&sh7[48 * (kBlock * 4) + sb]) = toh4(l);
    }

    // ---- Stream a5: 3x8 batches + 1 ----
    float4 s5v = zero, c5v = zero;
#pragma unroll
    for (int ch = 0; ch < 3; ++ch) {
        float4 buf[8];
#pragma unroll
        for (int j = 0; j < 8; ++j) buf[j] = ld4(a5p + (size_t)(ch * 8 + j) * kHW);
#pragma unroll
        for (int j = 0; j < 8; ++j) {
            int c = ch * 8 + j;
            if (c == 12) c5v = buf[j];
            s5v = f4add(s5v, f4abs(buf[j]));
            *(half4*)(&sh5[c * (kBlock * 4) + sb]) = toh4(buf[j]);
        }
    }
    {
        float4 l = ld4(a5p + (size_t)24 * kHW);
        s5v = f4add(s5v, f4abs(l));
        *(half4*)(&sh5[24 * (kBlock * 4) + sb]) = toh4(l);
    }

    // ---- a3 stays in registers (9 float4 = 36 VGPR) ----
    float4 a3r[9];
    float4 s3v = zero;
#pragma unroll
    for (int c = 0; c < 9; ++c) a3r[c] = ld4(a3p + (size_t)c * kHW);
#pragma unroll
    for (int c = 0; c < 9; ++c) s3v = f4add(s3v, f4abs(a3r[c]));

    // ---- Per-pixel scalars ----
    float4 g0 = ld4(sgp);
    float4 g1 = ld4(sgp + kHW);
    float4 g2 = ld4(sgp + 2 * kHW);
    float4 mx = f4max(g0, f4max(g1, g2));
    float4 e0 = make_float4(expf(g0.x - mx.x), expf(g0.y - mx.y), expf(g0.z - mx.z), expf(g0.w - mx.w));
    float4 e1 = make_float4(expf(g1.x - mx.x), expf(g1.y - mx.y), expf(g1.z - mx.z), expf(g1.w - mx.w));
    float4 e2 = make_float4(expf(g2.x - mx.x), expf(g2.y - mx.y), expf(g2.z - mx.z), expf(g2.w - mx.w));
    float4 einv = make_float4(1.f / (e0.x + e1.x + e2.x), 1.f / (e0.y + e1.y + e2.y),
                              1.f / (e0.z + e1.z + e2.z), 1.f / (e0.w + e1.w + e2.w));

    float4 alv = ld4(AL + p);
    float4 ml  = ld4(ML + p);
    float4 al = make_float4(fminf(fmaxf(alv.x, 0.f), 1.f), fminf(fmaxf(alv.y, 0.f), 1.f),
                            fminf(fmaxf(alv.z, 0.f), 1.f), fminf(fmaxf(alv.w, 0.f), 1.f));
    float4 mk = make_float4(ml.x > 0.5f ? 1.f : 0.f, ml.y > 0.5f ? 1.f : 0.f,
                            ml.z > 0.5f ? 1.f : 0.f, ml.w > 0.5f ? 1.f : 0.f);
    float4 g = f4mul(al, mk);
    float4 omg = make_float4(1.f - g.x, 1.f - g.y, 1.f - g.z, 1.f - g.w);

    float4 w3 = make_float4(omg.x * e0.x * einv.x / (s3v.x + kEps), omg.y * e0.y * einv.y / (s3v.y + kEps),
                            omg.z * e0.z * einv.z / (s3v.z + kEps), omg.w * e0.w * einv.w / (s3v.w + kEps));
    float4 w5 = make_float4(omg.x * e1.x * einv.x / (s5v.x + kEps), omg.y * e1.y * einv.y / (s5v.y + kEps),
                            omg.z * e1.z * einv.z / (s5v.z + kEps), omg.w * e1.w * einv.w / (s5v.w + kEps));
    float4 w7 = make_float4(omg.x * e2.x * einv.x / (s7v.x + kEps), omg.y * e2.y * einv.y / (s7v.y + kEps),
                            omg.z * e2.z * einv.z / (s7v.z + kEps), omg.w * e2.w * einv.w / (s7v.w + kEps));

    // Q = (w3*c3 + w5*c5 + w7*c7)*D0 + g*DL   (center Dt coef cancels)
    {
        float4 d0 = ld4(D0 + p);
        float4 dl = ld4(DL + p);
        float4 cw = f4fma(w3, a3r[4], f4fma(w5, c5v, f4mul(w7, c7v)));
        *(float4*)(&g_Q[p]) = f4fma(cw, d0, f4mul(g, dl));
    }

    // ---- Merge from LDS (own slots; no barrier needed) + store fp16 ----
    int oi = 0;
#pragma unroll
    for (int i = 0; i < 49; ++i) {
        int dy = i / 7 - 3, dx = i % 7 - 3;
        if (dy == 0 && dx == 0) continue;
        float4 a7v = tof4(*(const half4*)(&sh7[i * (kBlock * 4) + sb]));
        float4 wv = f4mul(w7, a7v);
        if (dy >= -2 && dy <= 2 && dx >= -2 && dx <= 2) {
            float4 a5v = tof4(*(const half4*)(&sh5[((dy + 2) * 5 + (dx + 2)) * (kBlock * 4) + sb]));
            wv = f4fma(w5, a5v, wv);
        }
        if (dy >= -1 && dy <= 1 && dx >= -1 && dx <= 1)
            wv = f4fma(w3, a3r[(dy + 1) * 3 + (dx + 1)], wv);
        *(half4*)(&g_Wh[(size_t)oi * kN + p]) = toh4(wv);
        ++oi;
    }
}

// One propagation step, 8 pixels/thread (R10 kernel, verbatim — ~11 us):
// Wh loads half8 (16 B/lane); rows via 4 all-or-nothing float4 segments.
__global__ __launch_bounds__(kBlock) void step_kernel(
    const float* __restrict__ Din_ext, float* __restrict__ Dout_ext,
    int src_g, int dst_g)
{
    const float* Din = src_g ? g_ping : Din_ext;
    float* Dout = dst_g ? g_ping : Dout_ext;

    int t = blockIdx.x * kBlock + threadIdx.x;   // 0 .. kN/8-1
    int p = t * 8;
    int b = p / kHW;                             // kHW % 8 == 0
    int rem = p - b * kHW;
    int y = rem / kW;                            // kW % 8 == 0: stays in one row
    int x0 = rem - y * kW;
    const float* dinb = Din + (size_t)b * kHW;

    float acc[8];
    {
        float4 q0 = ld4(&g_Q[p]);
        float4 q1 = ld4(&g_Q[p + 4]);
        acc[0] = q0.x; acc[1] = q0.y; acc[2] = q0.z; acc[3] = q0.w;
        acc[4] = q1.x; acc[5] = q1.y; acc[6] = q1.z; acc[7] = q1.w;
    }

    int oi = 0;
#pragma unroll
    for (int dy = -3; dy <= 3; ++dy) {
        int ny = y + dy;
        bool rv = (ny >= 0) && (ny < kH);
        if (!rv) { oi += (dy == 0) ? 6 : 7; continue; }   // zero contribution
        const float* dr = dinb + ny * kW;

        float rowv[16];   // covers x0-4 .. x0+11
#pragma unroll
        for (int s = 0; s < 4; ++s) {
            int xb = x0 + (s - 1) * 4;
            float4 v = (xb >= 0 && xb + 3 < kW) ? ld4(dr + xb)
                                                : make_float4(0.f, 0.f, 0.f, 0.f);
            rowv[s * 4 + 0] = v.x; rowv[s * 4 + 1] = v.y;
            rowv[s * 4 + 2] = v.z; rowv[s * 4 + 3] = v.w;
        }
#pragma unroll
        for (int dx = -3; dx <= 3; ++dx) {
            if (dy == 0 && dx == 0) continue;
            half8 w = *(const half8*)(&g_Wh[(size_t)oi * kN + p]);
#pragma unroll
            for (int j = 0; j < 8; ++j)
                acc[j] = fmaf((float)w[j], rowv[4 + j + dx], acc[j]);
            ++oi;
        }
    }

#pragma unroll
    for (int j = 0; j < 8; ++j)
        acc[j] = fminf(fmaxf(acc[j], 0.f), kDmax);
    *(float4*)(&Dout[p])     = make_float4(acc[0], acc[1], acc[2], acc[3]);
    *(float4*)(&Dout[p + 4]) = make_float4(acc[4], acc[5], acc[6], acc[7]);
}

extern "C" void kernel_launch(void* const* d_in, const int* in_sizes, int n_in,
                              void* d_out, int out_size, void* d_ws, size_t ws_size,
                              hipStream_t stream) {
    const float* D0 = (const float*)d_in[0];
    const float* DL = (const float*)d_in[1];
    const float* ML = (const float*)d_in[2];
    const float* A3 = (const float*)d_in[3];
    const float* A5 = (const float*)d_in[4];
    const float* A7 = (const float*)d_in[5];
    const float* SG = (const float*)d_in[6];
    const float* AL = (const float*)d_in[7];
    float* out = (float*)d_out;

    dim3 block(kBlock);
    dim3 gridQ(kN / 4 / kBlock);   // 836, exact  (prep: 4 px/thread)
    dim3 gridO(kN / 8 / kBlock);   // 418, exact  (steps: 8 px/thread)

    prep_kernel<<<gridQ, block, 0, stream>>>(D0, DL, ML, A3, A5, A7, SG, AL);

    // Chain: D0 -> ping -> out -> ping -> out -> ping -> out
    step_kernel<<<gridO, block, 0, stream>>>(D0, nullptr, 0, 1);
    step_kernel<<<gridO, block, 0, stream>>>(nullptr, out, 1, 0);
    step_kernel<<<gridO, block, 0, stream>>>(out, nullptr, 0, 1);
    step_kernel<<<gridO, block, 0, stream>>>(nullptr, out, 1, 0);
    step_kernel<<<gridO, block, 0, stream>>>(out, nullptr, 0, 1);
    step_kernel<<<gridO, block, 0, stream>>>(nullptr, out, 1, 0);
}

// Round 14
// 193.532 us; speedup vs baseline: 1.2541x; 1.0148x over previous
//
#include <hip/hip_runtime.h>

namespace {
constexpr int kB = 2;
constexpr int kH = 352;
constexpr int kW = 1216;
constexpr int kHW = kH * kW;        // 428032
constexpr int kN = kB * kHW;        // 856064
constexpr float kDmax = 80.0f;
constexpr float kEps = 1e-6f;
constexpr int kBlock = 256;         // step kernels
constexpr int kBlockP = 128;        // prep: 74 KB stash -> 2 blocks/CU = 8 waves/CU
}

typedef _Float16 half_t;
typedef __attribute__((ext_vector_type(4))) _Float16 half4;
typedef __attribute__((ext_vector_type(8))) _Float16 half8;

// Module-owned workspace, fully rewritten from inputs on every launch.
__device__ half_t g_Wh[(size_t)48 * kN];  // merged weights, fp16, ch-major (~82 MB)
__device__ float  g_Q[kN];                // fp32 constant term
__device__ float  g_ping[kN];             // Dt ping buffer

__device__ __forceinline__ float4 ld4(const float* p) { return *(const float4*)p; }
__device__ __forceinline__ float4 f4add(float4 a, float4 b) {
    return make_float4(a.x + b.x, a.y + b.y, a.z + b.z, a.w + b.w);
}
__device__ __forceinline__ float4 f4mul(float4 a, float4 b) {
    return make_float4(a.x * b.x, a.y * b.y, a.z * b.z, a.w * b.w);
}
__device__ __forceinline__ float4 f4fma(float4 a, float4 b, float4 c) {
    return make_float4(fmaf(a.x, b.x, c.x), fmaf(a.y, b.y, c.y),
                       fmaf(a.z, b.z, c.z), fmaf(a.w, b.w, c.w));
}
__device__ __forceinline__ float4 f4abs(float4 a) {
    return make_float4(fabsf(a.x), fabsf(a.y), fabsf(a.z), fabsf(a.w));
}
__device__ __forceinline__ float4 f4max(float4 a, float4 b) {
    return make_float4(fmaxf(a.x, b.x), fmaxf(a.y, b.y),
                       fmaxf(a.z, b.z), fmaxf(a.w, b.w));
}
__device__ __forceinline__ half4 toh4(float4 v) {
    half4 h;
    h[0] = (half_t)v.x; h[1] = (half_t)v.y; h[2] = (half_t)v.z; h[3] = (half_t)v.w;
    return h;
}
__device__ __forceinline__ float4 tof4(half4 h) {
    return make_float4((float)h[0], (float)h[1], (float)h[2], (float)h[3]);
}

// Single-pass merged-weight precompute. R13 structure unchanged EXCEPT block
// size 256 -> 128: stash drops 148 KB -> 74 KB => 2 blocks/CU = 8 waves/CU
// (was 1 block = 4 waves, OccupancyPercent 9.4). Clean A/B of "cold-read
// wall" vs "in-flight concurrency" theories: same per-thread instruction
// stream, same 16 B/lane loads, same traffic; only resident-wave count
// doubles. Little's-law predicts ~2x if concurrency-limited.
__global__ __launch_bounds__(kBlockP) void prep_kernel(
    const float* __restrict__ D0, const float* __restrict__ DL,
    const float* __restrict__ ML, const float* __restrict__ A3,
    const float* __restrict__ A5, const float* __restrict__ A7,
    const float* __restrict__ SG, const float* __restrict__ AL)
{
    __shared__ half_t sh7[49 * kBlockP * 4];   // 50176 B
    __shared__ half_t sh5[25 * kBlockP * 4];   // 25600 B  (total 74 KiB)

    int tid = threadIdx.x;
    int t = blockIdx.x * kBlockP + tid;       // 0 .. kN/4-1
    int p = t * 4;
    int b = p / kHW;                          // kHW % 512 == 0: block batch-uniform
    int rem = p - b * kHW;
    int sb = tid * 4;                         // this thread's LDS pixel base

    const float* a3p = A3 + (size_t)b * 9 * kHW + rem;
    const float* a5p = A5 + (size_t)b * 25 * kHW + rem;
    const float* a7p = A7 + (size_t)b * 49 * kHW + rem;
    const float* sgp = SG + (size_t)b * 3 * kHW + rem;

    float4 zero = make_float4(0.f, 0.f, 0.f, 0.f);

    // ---- Stream a7: 6x8 batches + 1; abs-sum, stash fp16 ----
    float4 s7v = zero, c7v = zero;
#pragma unroll
    for (int ch = 0; ch < 6; ++ch) {
        float4 buf[8];
#pragma unroll
        for (int j = 0; j < 8; ++j) buf[j] = ld4(a7p + (size_t)(ch * 8 + j) * kHW);
#pragma unroll
        for (int j = 0; j < 8; ++j) {
            int c = ch * 8 + j;
            if (c == 24) c7v = buf[j];
            s7v = f4add(s7v, f4abs(buf[j]));
            *(half4*)(&sh7[c * (kBlockP * 4) + sb]) = toh4(buf[j]);
        }
    }
    {
        float4 l = ld4(a7p + (size_t)48 * kHW);
        s7v = f4add(s7v, f4abs(l));
        *(half4*)(&sh7[48 * (kBlockP * 4) + sb]) = toh4(l);
    }

    // ---- Stream a5: 3x8 batches + 1 ----
    float4 s5v = zero, c5v = zero;
#pragma unroll
    for (int ch = 0; ch < 3; ++ch) {
        float4 buf[8];
#pragma unroll
        for (int j = 0; j < 8; ++j) buf[j] = ld4(a5p + (size_t)(ch * 8 + j) * kHW);
#pragma unroll
        for (int j = 0; j < 8; ++j) {
            int c = ch * 8 + j;
            if (c == 12) c5v = buf[j];
            s5v = f4add(s5v, f4abs(buf[j]));
            *(half4*)(&sh5[c * (kBlockP * 4) + sb]) = toh4(buf[j]);
        }
    }
    {
        float4 l = ld4(a5p + (size_t)24 * kHW);
        s5v = f4add(s5v, f4abs(l));
        *(half4*)(&sh5[24 * (kBlockP * 4) + sb]) = toh4(l);
    }

    // ---- a3 stays in registers (9 float4 = 36 VGPR) ----
    float4 a3r[9];
    float4 s3v = zero;
#pragma unroll
    for (int c = 0; c < 9; ++c) a3r[c] = ld4(a3p + (size_t)c * kHW);
#pragma unroll
    for (int c = 0; c < 9; ++c) s3v = f4add(s3v, f4abs(a3r[c]));

    // ---- Per-pixel scalars ----
    float4 g0 = ld4(sgp);
    float4 g1 = ld4(sgp + kHW);
    float4 g2 = ld4(sgp + 2 * kHW);
    float4 mx = f4max(g0, f4max(g1, g2));
    float4 e0 = make_float4(expf(g0.x - mx.x), expf(g0.y - mx.y), expf(g0.z - mx.z), expf(g0.w - mx.w));
    float4 e1 = make_float4(expf(g1.x - mx.x), expf(g1.y - mx.y), expf(g1.z - mx.z), expf(g1.w - mx.w));
    float4 e2 = make_float4(expf(g2.x - mx.x), expf(g2.y - mx.y), expf(g2.z - mx.z), expf(g2.w - mx.w));
    float4 einv = make_float4(1.f / (e0.x + e1.x + e2.x), 1.f / (e0.y + e1.y + e2.y),
                              1.f / (e0.z + e1.z + e2.z), 1.f / (e0.w + e1.w + e2.w));

    float4 alv = ld4(AL + p);
    float4 ml  = ld4(ML + p);
    float4 al = make_float4(fminf(fmaxf(alv.x, 0.f), 1.f), fminf(fmaxf(alv.y, 0.f), 1.f),
                            fminf(fmaxf(alv.z, 0.f), 1.f), fminf(fmaxf(alv.w, 0.f), 1.f));
    float4 mk = make_float4(ml.x > 0.5f ? 1.f : 0.f, ml.y > 0.5f ? 1.f : 0.f,
                            ml.z > 0.5f ? 1.f : 0.f, ml.w > 0.5f ? 1.f : 0.f);
    float4 g = f4mul(al, mk);
    float4 omg = make_float4(1.f - g.x, 1.f - g.y, 1.f - g.z, 1.f - g.w);

    float4 w3 = make_float4(omg.x * e0.x * einv.x / (s3v.x + kEps), omg.y * e0.y * einv.y / (s3v.y + kEps),
                            omg.z * e0.z * einv.z / (s3v.z + kEps), omg.w * e0.w * einv.w / (s3v.w + kEps));
    float4 w5 = make_float4(omg.x * e1.x * einv.x / (s5v.x + kEps), omg.y * e1.y * einv.y / (s5v.y + kEps),
                            omg.z * e1.z * einv.z / (s5v.z + kEps), omg.w * e1.w * einv.w / (s5v.w + kEps));
    float4 w7 = make_float4(omg.x * e2.x * einv.x / (s7v.x + kEps), omg.y * e2.y * einv.y / (s7v.y + kEps),
                            omg.z * e2.z * einv.z / (s7v.z + kEps), omg.w * e2.w * einv.w / (s7v.w + kEps));

    // Q = (w3*c3 + w5*c5 + w7*c7)*D0 + g*DL   (center Dt coef cancels)
    {
        float4 d0 = ld4(D0 + p);
        float4 dl = ld4(DL + p);
        float4 cw = f4fma(w3, a3r[4], f4fma(w5, c5v, f4mul(w7, c7v)));
        *(float4*)(&g_Q[p]) = f4fma(cw, d0, f4mul(g, dl));
    }

    // ---- Merge from LDS (own slots; no barrier needed) + store fp16 ----
    int oi = 0;
#pragma unroll
    for (int i = 0; i < 49; ++i) {
        int dy = i / 7 - 3, dx = i % 7 - 3;
        if (dy == 0 && dx == 0) continue;
        float4 a7v = tof4(*(const half4*)(&sh7[i * (kBlockP * 4) + sb]));
        float4 wv = f4mul(w7, a7v);
        if (dy >= -2 && dy <= 2 && dx >= -2 && dx <= 2) {
            float4 a5v = tof4(*(const half4*)(&sh5[((dy + 2) * 5 + (dx + 2)) * (kBlockP * 4) + sb]));
            wv = f4fma(w5, a5v, wv);
        }
        if (dy >= -1 && dy <= 1 && dx >= -1 && dx <= 1)
            wv = f4fma(w3, a3r[(dy + 1) * 3 + (dx + 1)], wv);
        *(half4*)(&g_Wh[(size_t)oi * kN + p]) = toh4(wv);
        ++oi;
    }
}

// One propagation step, 8 pixels/thread (frozen — ~11 us, L3-rate).
__global__ __launch_bounds__(kBlock) void step_kernel(
    const float* __restrict__ Din_ext, float* __restrict__ Dout_ext,
    int src_g, int dst_g)
{
    const float* Din = src_g ? g_ping : Din_ext;
    float* Dout = dst_g ? g_ping : Dout_ext;

    int t = blockIdx.x * kBlock + threadIdx.x;   // 0 .. kN/8-1
    int p = t * 8;
    int b = p / kHW;                             // kHW % 8 == 0
    int rem = p - b * kHW;
    int y = rem / kW;                            // kW % 8 == 0: stays in one row
    int x0 = rem - y * kW;
    const float* dinb = Din + (size_t)b * kHW;

    float acc[8];
    {
        float4 q0 = ld4(&g_Q[p]);
        float4 q1 = ld4(&g_Q[p + 4]);
        acc[0] = q0.x; acc[1] = q0.y; acc[2] = q0.z; acc[3] = q0.w;
        acc[4] = q1.x; acc[5] = q1.y; acc[6] = q1.z; acc[7] = q1.w;
    }

    int oi = 0;
#pragma unroll
    for (int dy = -3; dy <= 3; ++dy) {
        int ny = y + dy;
        bool rv = (ny >= 0) && (ny < kH);
        if (!rv) { oi += (dy == 0) ? 6 : 7; continue; }   // zero contribution
        const float* dr = dinb + ny * kW;

        float rowv[16];   // covers x0-4 .. x0+11
#pragma unroll
        for (int s = 0; s < 4; ++s) {
            int xb = x0 + (s - 1) * 4;
            float4 v = (xb >= 0 && xb + 3 < kW) ? ld4(dr + xb)
                                                : make_float4(0.f, 0.f, 0.f, 0.f);
            rowv[s * 4 + 0] = v.x; rowv[s * 4 + 1] = v.y;
            rowv[s * 4 + 2] = v.z; rowv[s * 4 + 3] = v.w;
        }
#pragma unroll
        for (int dx = -3; dx <= 3; ++dx) {
            if (dy == 0 && dx == 0) continue;
            half8 w = *(const half8*)(&g_Wh[(size_t)oi * kN + p]);
#pragma unroll
            for (int j = 0; j < 8; ++j)
                acc[j] = fmaf((float)w[j], rowv[4 + j + dx], acc[j]);
            ++oi;
        }
    }

#pragma unroll
    for (int j = 0; j < 8; ++j)
        acc[j] = fminf(fmaxf(acc[j], 0.f), kDmax);
    *(float4*)(&Dout[p])     = make_float4(acc[0], acc[1], acc[2], acc[3]);
    *(float4*)(&Dout[p + 4]) = make_float4(acc[4], acc[5], acc[6], acc[7]);
}

extern "C" void kernel_launch(void* const* d_in, const int* in_sizes, int n_in,
                              void* d_out, int out_size, void* d_ws, size_t ws_size,
                              hipStream_t stream) {
    const float* D0 = (const float*)d_in[0];
    const float* DL = (const float*)d_in[1];
    const float* ML = (const float*)d_in[2];
    const float* A3 = (const float*)d_in[3];
    const float* A5 = (const float*)d_in[4];
    const float* A7 = (const float*)d_in[5];
    const float* SG = (const float*)d_in[6];
    const float* AL = (const float*)d_in[7];
    float* out = (float*)d_out;

    dim3 gridP(kN / 4 / kBlockP);   // 1672, exact  (prep: 4 px/thread, 128-thr blocks)
    dim3 gridO(kN / 8 / kBlock);    // 418, exact   (steps: 8 px/thread)

    prep_kernel<<<gridP, dim3(kBlockP), 0, stream>>>(D0, DL, ML, A3, A5, A7, SG, AL);

    // Chain: D0 -> ping -> out -> ping -> out -> ping -> out
    step_kernel<<<gridO, dim3(kBlock), 0, stream>>>(D0, nullptr, 0, 1);
    step_kernel<<<gridO, dim3(kBlock), 0, stream>>>(nullptr, out, 1, 0);
    step_kernel<<<gridO, dim3(kBlock), 0, stream>>>(out, nullptr, 0, 1);
    step_kernel<<<gridO, dim3(kBlock), 0, stream>>>(nullptr, out, 1, 0);
    step_kernel<<<gridO, dim3(kBlock), 0, stream>>>(out, nullptr, 0, 1);
    step_kernel<<<gridO, dim3(kBlock), 0, stream>>>(nullptr, out, 1, 0);
}

// Round 15
// 189.532 us; speedup vs baseline: 1.2806x; 1.0211x over previous
//
#include <hip/hip_runtime.h>

namespace {
constexpr int kB = 2;
constexpr int kH = 352;
constexpr int kW = 1216;
constexpr int kHW = kH * kW;        // 428032
constexpr int kN = kB * kHW;        // 856064
constexpr float kDmax = 80.0f;
constexpr float kEps = 1e-6f;
constexpr int kBlock = 256;         // step kernels
constexpr int kBlockP = 128;        // prep blocks
constexpr int kStepGrid = 512;      // exactly 2 blocks/CU
constexpr int kUnitsPerBlk = 209;   // 512*209 = kN/8 exactly -> perfect balance
}

typedef _Float16 half_t;
typedef __attribute__((ext_vector_type(4))) _Float16 half4;
typedef __attribute__((ext_vector_type(8))) _Float16 half8;

// Module-owned workspace, fully rewritten from inputs on every launch.
__device__ half_t g_Wh[(size_t)48 * kN];  // merged weights, fp16, ch-major (~82 MB)
__device__ float  g_Q[kN];                // fp32 constant term
__device__ float  g_ping[kN];             // Dt ping buffer

__device__ __forceinline__ float4 ld4(const float* p) { return *(const float4*)p; }
__device__ __forceinline__ float4 f4add(float4 a, float4 b) {
    return make_float4(a.x + b.x, a.y + b.y, a.z + b.z, a.w + b.w);
}
__device__ __forceinline__ float4 f4mul(float4 a, float4 b) {
    return make_float4(a.x * b.x, a.y * b.y, a.z * b.z, a.w * b.w);
}
__device__ __forceinline__ float4 f4fma(float4 a, float4 b, float4 c) {
    return make_float4(fmaf(a.x, b.x, c.x), fmaf(a.y, b.y, c.y),
                       fmaf(a.z, b.z, c.z), fmaf(a.w, b.w, c.w));
}
__device__ __forceinline__ float4 f4abs(float4 a) {
    return make_float4(fabsf(a.x), fabsf(a.y), fabsf(a.z), fabsf(a.w));
}
__device__ __forceinline__ float4 f4max(float4 a, float4 b) {
    return make_float4(fmaxf(a.x, b.x), fmaxf(a.y, b.y),
                       fmaxf(a.z, b.z), fmaxf(a.w, b.w));
}
__device__ __forceinline__ half4 toh4(float4 v) {
    half4 h;
    h[0] = (half_t)v.x; h[1] = (half_t)v.y; h[2] = (half_t)v.z; h[3] = (half_t)v.w;
    return h;
}
__device__ __forceinline__ float4 tof4(half4 h) {
    return make_float4((float)h[0], (float)h[1], (float)h[2], (float)h[3]);
}

// Single-pass merged-weight precompute + FUSED FIRST STEP.
// R14 lessons: (a) stash LDS footprint (37 KB/wave) caps prep at 4 waves/CU
// regardless of block size; replay runs (L3-warm inputs) take identical time
// -> prep is internal-latency-bound at ~127 us, not HBM-bound. (b) So stop
// optimizing prep's read; instead ABSORB step 1: the merge loop holds each
// pixel's fp32 merged weight wv in registers, step 1's input is D0 (L3-hot,
// 3.4 MB) -> accumulate acc += wv * D0[neighbor] while storing Wh, write D1
// to g_ping. Eliminates one full step dispatch (92 MB L3 reads, ~11 us).
__global__ __launch_bounds__(kBlockP) void prep_kernel(
    const float* __restrict__ D0, const float* __restrict__ DL,
    const float* __restrict__ ML, const float* __restrict__ A3,
    const float* __restrict__ A5, const float* __restrict__ A7,
    const float* __restrict__ SG, const float* __restrict__ AL)
{
    __shared__ half_t sh7[49 * kBlockP * 4];   // 50176 B
    __shared__ half_t sh5[25 * kBlockP * 4];   // 25600 B  (total 74 KiB)

    int tid = threadIdx.x;
    int t = blockIdx.x * kBlockP + tid;       // 0 .. kN/4-1
    int p = t * 4;
    int b = p / kHW;                          // kHW % 512 == 0: block batch-uniform
    int rem = p - b * kHW;
    int y = rem / kW;                         // kW % 4 == 0: 4-px group stays in row
    int x0 = rem - y * kW;
    int sb = tid * 4;                         // this thread's LDS pixel base

    const float* a3p = A3 + (size_t)b * 9 * kHW + rem;
    const float* a5p = A5 + (size_t)b * 25 * kHW + rem;
    const float* a7p = A7 + (size_t)b * 49 * kHW + rem;
    const float* sgp = SG + (size_t)b * 3 * kHW + rem;
    const float* d0b = D0 + (size_t)b * kHW;

    float4 zero = make_float4(0.f, 0.f, 0.f, 0.f);

    // ---- Stream a7: 6x8 batches + 1; abs-sum, stash fp16 ----
    float4 s7v = zero, c7v = zero;
#pragma unroll
    for (int ch = 0; ch < 6; ++ch) {
        float4 buf[8];
#pragma unroll
        for (int j = 0; j < 8; ++j) buf[j] = ld4(a7p + (size_t)(ch * 8 + j) * kHW);
#pragma unroll
        for (int j = 0; j < 8; ++j) {
            int c = ch * 8 + j;
            if (c == 24) c7v = buf[j];
            s7v = f4add(s7v, f4abs(buf[j]));
            *(half4*)(&sh7[c * (kBlockP * 4) + sb]) = toh4(buf[j]);
        }
    }
    {
        float4 l = ld4(a7p + (size_t)48 * kHW);
        s7v = f4add(s7v, f4abs(l));
        *(half4*)(&sh7[48 * (kBlockP * 4) + sb]) = toh4(l);
    }

    // ---- Stream a5: 3x8 batches + 1 ----
    float4 s5v = zero, c5v = zero;
#pragma unroll
    for (int ch = 0; ch < 3; ++ch) {
        float4 buf[8];
#pragma unroll
        for (int j = 0; j < 8; ++j) buf[j] = ld4(a5p + (size_t)(ch * 8 + j) * kHW);
#pragma unroll
        for (int j = 0; j < 8; ++j) {
            int c = ch * 8 + j;
            if (c == 12) c5v = buf[j];
            s5v = f4add(s5v, f4abs(buf[j]));
            *(half4*)(&sh5[c * (kBlockP * 4) + sb]) = toh4(buf[j]);
        }
    }
    {
        float4 l = ld4(a5p + (size_t)24 * kHW);
        s5v = f4add(s5v, f4abs(l));
        *(half4*)(&sh5[24 * (kBlockP * 4) + sb]) = toh4(l);
    }

    // ---- a3 stays in registers (9 float4 = 36 VGPR) ----
    float4 a3r[9];
    float4 s3v = zero;
#pragma unroll
    for (int c = 0; c < 9; ++c) a3r[c] = ld4(a3p + (size_t)c * kHW);
#pragma unroll
    for (int c = 0; c < 9; ++c) s3v = f4add(s3v, f4abs(a3r[c]));

    // ---- Per-pixel scalars ----
    float4 g0 = ld4(sgp);
    float4 g1 = ld4(sgp + kHW);
    float4 g2 = ld4(sgp + 2 * kHW);
    float4 mx = f4max(g0, f4max(g1, g2));
    float4 e0 = make_float4(expf(g0.x - mx.x), expf(g0.y - mx.y), expf(g0.z - mx.z), expf(g0.w - mx.w));
    float4 e1 = make_float4(expf(g1.x - mx.x), expf(g1.y - mx.y), expf(g1.z - mx.z), expf(g1.w - mx.w));
    float4 e2 = make_float4(expf(g2.x - mx.x), expf(g2.y - mx.y), expf(g2.z - mx.z), expf(g2.w - mx.w));
    float4 einv = make_float4(1.f / (e0.x + e1.x + e2.x), 1.f / (e0.y + e1.y + e2.y),
                              1.f / (e0.z + e1.z + e2.z), 1.f / (e0.w + e1.w + e2.w));

    float4 alv = ld4(AL + p);
    float4 ml  = ld4(ML + p);
    float4 al = make_float4(fminf(fmaxf(alv.x, 0.f), 1.f), fminf(fmaxf(alv.y, 0.f), 1.f),
                            fminf(fmaxf(alv.z, 0.f), 1.f), fminf(fmaxf(alv.w, 0.f), 1.f));
    float4 mk = make_float4(ml.x > 0.5f ? 1.f : 0.f, ml.y > 0.5f ? 1.f : 0.f,
                            ml.z > 0.5f ? 1.f : 0.f, ml.w > 0.5f ? 1.f : 0.f);
    float4 g = f4mul(al, mk);
    float4 omg = make_float4(1.f - g.x, 1.f - g.y, 1.f - g.z, 1.f - g.w);

    float4 w3 = make_float4(omg.x * e0.x * einv.x / (s3v.x + kEps), omg.y * e0.y * einv.y / (s3v.y + kEps),
                            omg.z * e0.z * einv.z / (s3v.z + kEps), omg.w * e0.w * einv.w / (s3v.w + kEps));
    float4 w5 = make_float4(omg.x * e1.x * einv.x / (s5v.x + kEps), omg.y * e1.y * einv.y / (s5v.y + kEps),
                            omg.z * e1.z * einv.z / (s5v.z + kEps), omg.w * e1.w * einv.w / (s5v.w + kEps));
    float4 w7 = make_float4(omg.x * e2.x * einv.x / (s7v.x + kEps), omg.y * e2.y * einv.y / (s7v.y + kEps),
                            omg.z * e2.z * einv.z / (s7v.z + kEps), omg.w * e2.w * einv.w / (s7v.w + kEps));

    // Q = (w3*c3 + w5*c5 + w7*c7)*D0 + g*DL   (center Dt coef cancels)
    float4 d0 = ld4(D0 + p);
    float4 dl = ld4(DL + p);
    float4 cw = f4fma(w3, a3r[4], f4fma(w5, c5v, f4mul(w7, c7v)));
    float4 Qv = f4fma(cw, d0, f4mul(g, dl));
    *(float4*)(&g_Q[p]) = Qv;

    // ---- Merge from LDS + store fp16 Wh + FUSED STEP 1 (acc on fp32 wv) ----
    float acc[4] = {Qv.x, Qv.y, Qv.z, Qv.w};
    int oi = 0;
#pragma unroll
    for (int dy = -3; dy <= 3; ++dy) {
        int ny = y + dy;
        bool rv = (ny >= 0) && (ny < kH);
        float rowv[12];   // D0 row window, x0-4 .. x0+7
        if (rv) {
            const float* dr = d0b + ny * kW;
#pragma unroll
            for (int s = 0; s < 3; ++s) {
                int xb = x0 + (s - 1) * 4;
                float4 v = (xb >= 0 && xb + 3 < kW) ? ld4(dr + xb) : zero;
                rowv[s * 4 + 0] = v.x; rowv[s * 4 + 1] = v.y;
                rowv[s * 4 + 2] = v.z; rowv[s * 4 + 3] = v.w;
            }
        } else {
#pragma unroll
            for (int s = 0; s < 12; ++s) rowv[s] = 0.f;
        }
#pragma unroll
        for (int dx = -3; dx <= 3; ++dx) {
            if (dy == 0 && dx == 0) continue;
            int i = (dy + 3) * 7 + (dx + 3);
            float4 wv = f4mul(w7, tof4(*(const half4*)(&sh7[i * (kBlockP * 4) + sb])));
            if (dy >= -2 && dy <= 2 && dx >= -2 && dx <= 2)
                wv = f4fma(w5, tof4(*(const half4*)(&sh5[((dy + 2) * 5 + (dx + 2)) * (kBlockP * 4) + sb])), wv);
            if (dy >= -1 && dy <= 1 && dx >= -1 && dx <= 1)
                wv = f4fma(w3, a3r[(dy + 1) * 3 + (dx + 1)], wv);
            *(half4*)(&g_Wh[(size_t)oi * kN + p]) = toh4(wv);
            acc[0] = fmaf(wv.x, rowv[4 + 0 + dx], acc[0]);
            acc[1] = fmaf(wv.y, rowv[4 + 1 + dx], acc[1]);
            acc[2] = fmaf(wv.z, rowv[4 + 2 + dx], acc[2]);
            acc[3] = fmaf(wv.w, rowv[4 + 3 + dx], acc[3]);
            ++oi;
        }
    }
    float4 o;
    o.x = fminf(fmaxf(acc[0], 0.f), kDmax);
    o.y = fminf(fmaxf(acc[1], 0.f), kDmax);
    o.z = fminf(fmaxf(acc[2], 0.f), kDmax);
    o.w = fminf(fmaxf(acc[3], 0.f), kDmax);
    *(float4*)(&g_ping[p]) = o;               // D1
}

// One propagation step, 8 pixels/thread, BALANCED grid: 512 blocks (exactly
// 2/CU) x 209 active units (512*209 = kN/8). R14 analysis: 418-block grid
// gave worst-CU 2 blocks vs best 1 -> 22% makespan slack.
__global__ __launch_bounds__(kBlock) void step_kernel(
    const float* __restrict__ Din_ext, float* __restrict__ Dout_ext,
    int src_g, int dst_g)
{
    if (threadIdx.x >= kUnitsPerBlk) return;
    const float* Din = src_g ? g_ping : Din_ext;
    float* Dout = dst_g ? g_ping : Dout_ext;

    int t = blockIdx.x * kUnitsPerBlk + threadIdx.x;   // 0 .. kN/8-1
    int p = t * 8;
    int b = p / kHW;                             // kHW % 8 == 0
    int rem = p - b * kHW;
    int y = rem / kW;                            // kW % 8 == 0: stays in one row
    int x0 = rem - y * kW;
    const float* dinb = Din + (size_t)b * kHW;

    float acc[8];
    {
        float4 q0 = ld4(&g_Q[p]);
        float4 q1 = ld4(&g_Q[p + 4]);
        acc[0] = q0.x; acc[1] = q0.y; acc[2] = q0.z; acc[3] = q0.w;
        acc[4] = q1.x; acc[5] = q1.y; acc[6] = q1.z; acc[7] = q1.w;
    }

    int oi = 0;
#pragma unroll
    for (int dy = -3; dy <= 3; ++dy) {
        int ny = y + dy;
        bool rv = (ny >= 0) && (ny < kH);
        if (!rv) { oi += (dy == 0) ? 6 : 7; continue; }   // zero contribution
        const float* dr = dinb + ny * kW;

        float rowv[16];   // covers x0-4 .. x0+11
#pragma unroll
        for (int s = 0; s < 4; ++s) {
            int xb = x0 + (s - 1) * 4;
            float4 v = (xb >= 0 && xb + 3 < kW) ? ld4(dr + xb)
                                                : make_float4(0.f, 0.f, 0.f, 0.f);
            rowv[s * 4 + 0] = v.x; rowv[s * 4 + 1] = v.y;
            rowv[s * 4 + 2] = v.z; rowv[s * 4 + 3] = v.w;
        }
#pragma unroll
        for (int dx = -3; dx <= 3; ++dx) {
            if (dy == 0 && dx == 0) continue;
            half8 w = *(const half8*)(&g_Wh[(size_t)oi * kN + p]);
#pragma unroll
            for (int j = 0; j < 8; ++j)
                acc[j] = fmaf((float)w[j], rowv[4 + j + dx], acc[j]);
            ++oi;
        }
    }

#pragma unroll
    for (int j = 0; j < 8; ++j)
        acc[j] = fminf(fmaxf(acc[j], 0.f), kDmax);
    *(float4*)(&Dout[p])     = make_float4(acc[0], acc[1], acc[2], acc[3]);
    *(float4*)(&Dout[p + 4]) = make_float4(acc[4], acc[5], acc[6], acc[7]);
}

extern "C" void kernel_launch(void* const* d_in, const int* in_sizes, int n_in,
                              void* d_out, int out_size, void* d_ws, size_t ws_size,
                              hipStream_t stream) {
    const float* D0 = (const float*)d_in[0];
    const float* DL = (const float*)d_in[1];
    const float* ML = (const float*)d_in[2];
    const float* A3 = (const float*)d_in[3];
    const float* A5 = (const float*)d_in[4];
    const float* A7 = (const float*)d_in[5];
    const float* SG = (const float*)d_in[6];
    const float* AL = (const float*)d_in[7];
    float* out = (float*)d_out;

    dim3 gridP(kN / 4 / kBlockP);   // 1672, exact (prep: 4 px/thread, 128-thr blocks)
    dim3 gridS(kStepGrid);          // 512 = exactly 2 blocks/CU

    // prep computes Wh, Q AND D1 (fused step 1) -> g_ping
    prep_kernel<<<gridP, dim3(kBlockP), 0, stream>>>(D0, DL, ML, A3, A5, A7, SG, AL);

    // 5 remaining steps: ping -> out -> ping -> out -> ping -> out
    step_kernel<<<gridS, dim3(kBlock), 0, stream>>>(nullptr, out, 1, 0);
    step_kernel<<<gridS, dim3(kBlock), 0, stream>>>(out, nullptr, 0, 1);
    step_kernel<<<gridS, dim3(kBlock), 0, stream>>>(nullptr, out, 1, 0);
    step_kernel<<<gridS, dim3(kBlock), 0, stream>>>(out, nullptr, 0, 1);
    step_kernel<<<gridS, dim3(kBlock), 0, stream>>>(nullptr, out, 1, 0);
}